// Round 8
// baseline (221.088 us; speedup 1.0000x reference)
//
#include <hip/hip_runtime.h>
#include <hip/hip_bf16.h>
#include <math.h>

// Problem constants (MultiQueryAttention: B=2, S=2048, D=1024, H=16, hd=64)
#define BB 2
#define SS 2048
#define DD 1024
#define NH 16
#define HD 64
#define MM (BB * SS)  // 4096 tokens

#define BK 32            // GEMM k-step
#define NT (DD / BK)     // 32 k-steps

typedef __hip_bfloat16 bf16;
typedef __bf16 bf16_t;
typedef __attribute__((ext_vector_type(8))) __bf16 bf16x8;
typedef __attribute__((ext_vector_type(4))) __bf16 bf16x4;
typedef __attribute__((ext_vector_type(4))) float floatx4;

// (1/sqrt(64)) * log2(e): folded into Q at projection time so QK^T scores
// come out directly in the exp2 domain.
#define SCALEQ 0.18033688011112042f

// async global->LDS, 16B per lane (dest = wave-uniform base + lane*16)
__device__ __forceinline__ void gload16(const bf16_t* g, bf16_t* l) {
    __builtin_amdgcn_global_load_lds(
        (const __attribute__((address_space(1))) unsigned int*)g,
        (__attribute__((address_space(3))) unsigned int*)l,
        16, 0, 0);
}

// ---------------- runtime dtype detection (parallel) ----------------
// flag[0]==1 -> external tensors are fp32; flag[0]==0 -> bf16.
// flag[1] is always 0 (a "bf16" flag for the converted-input path).
__global__ void detect_dtype(const unsigned int* __restrict__ x, int* __restrict__ flag) {
    const int tid = threadIdx.x;  // 64 lanes
    int good = 0;
    for (int i = tid; i < 256; i += 64) {
        unsigned int bits = (x[i] & 0xFFFFu) << 16;
        float v = __uint_as_float(bits);
        float av = fabsf(v);
        if (av == 0.f || (av >= 9.5367431640625e-7f && av <= 64.f)) good++;
    }
#pragma unroll
    for (int s = 1; s < 64; s <<= 1) good += __shfl_xor(good, s);
    if (tid == 0) { flag[0] = (good >= 240) ? 0 : 1; flag[1] = 0; }
}

// ---------------- bulk fp32->bf16 conversion (or bf16 passthrough) -------
__device__ __forceinline__ void conv_seg(const void* __restrict__ in,
                                         bf16_t* __restrict__ out,
                                         int n, int f, int tid, int T) {
    if (f) {
        const float* p = (const float*)in;
        for (int i = tid * 8; i < n; i += T * 8) {
            float4 a = *(const float4*)(p + i);
            float4 b = *(const float4*)(p + i + 4);
            bf16x8 o;
            o[0] = (bf16_t)a.x; o[1] = (bf16_t)a.y; o[2] = (bf16_t)a.z; o[3] = (bf16_t)a.w;
            o[4] = (bf16_t)b.x; o[5] = (bf16_t)b.y; o[6] = (bf16_t)b.z; o[7] = (bf16_t)b.w;
            *(bf16x8*)(out + i) = o;
        }
    } else {
        const bf16_t* p = (const bf16_t*)in;
        for (int i = tid * 8; i < n; i += T * 8)
            *(bf16x8*)(out + i) = *(const bf16x8*)(p + i);
    }
}

__global__ __launch_bounds__(256) void conv_all(const void* __restrict__ x,
                                                const void* __restrict__ wq,
                                                const void* __restrict__ wk,
                                                const void* __restrict__ wv,
                                                const void* __restrict__ wo,
                                                bf16_t* __restrict__ xb,
                                                bf16_t* __restrict__ wqb,
                                                bf16_t* __restrict__ wkb,
                                                bf16_t* __restrict__ wvb,
                                                bf16_t* __restrict__ wob,
                                                const int* __restrict__ flag) {
    const int f = *flag;
    const int tid = blockIdx.x * blockDim.x + threadIdx.x;
    const int T = gridDim.x * blockDim.x;
    conv_seg(x, xb, MM * DD, f, tid, T);
    conv_seg(wq, wqb, DD * DD, f, tid, T);
    conv_seg(wk, wkb, HD * DD, f, tid, T);
    conv_seg(wv, wvb, HD * DD, f, tid, T);
    conv_seg(wo, wob, DD * DD, f, tid, T);
}

// ------- 128x128-tile bf16 projection GEMMs: global_load_lds staging -----
// 512 thr (8 waves 2x4, 64x32/wave, acc[4][2]). Staging is ONE
// global_load_lds(16B) per thread per operand per k-step: A/B tile = 128x32
// bf16 = 8 KB = 512 lanes x 16 B exactly. Double-buffered LDS, ONE barrier
// per k-step: tile t+1 loads issue at iteration top and fly under tile t's
// ds_read+MFMA; the compiler's vmcnt(0)-before-barrier drains them at the
// iteration end. gload_lds forces a LINEAR LDS dest (no padding), so
// conflict-free ds_read_b128 comes from an XOR swizzle applied on BOTH
// sides (rule #21): global source granule = (t&3)^(rS&3); read granule =
// quad^(lo&3). Lanes then spread 2/bank-group = free (m136).
__global__ __launch_bounds__(512) void proj_qkv_b(const bf16_t* __restrict__ X,
                                                  const bf16_t* __restrict__ Wq,
                                                  const bf16_t* __restrict__ Wk,
                                                  const bf16_t* __restrict__ Wv,
                                                  bf16_t* __restrict__ QA,
                                                  bf16_t* __restrict__ Kp,
                                                  bf16_t* __restrict__ VpT) {
    __shared__ bf16_t As[2][128 * BK];
    __shared__ bf16_t Bs[2][128 * BK];

    const int tid = threadIdx.x;
    const int wave = tid >> 6, lane = tid & 63;
    const int lo = lane & 15, quad = lane >> 4;
    const int qsw = quad ^ (lo & 3);          // swizzled read granule
    const int wr = wave >> 2, wc = wave & 3;  // 2x4 wave grid
    const int cb = blockIdx.x;                // 0..8 (8 => K|V fused)
    const int rowBase = blockIdx.y * 128;

    // staging: thread t covers LDS bytes [t*16, t*16+16) = row t>>2,
    // granule t&3; source granule swizzled by row.
    const int rS = tid >> 2;
    const int gsw = (((tid & 3) ^ (rS & 3)) * 8);

    const bf16_t* arow = X + (size_t)(rowBase + rS) * DD + gsw;
    const bf16_t* wrow;
    if (cb < 8)       wrow = Wq + (size_t)(cb * 128 + rS) * DD + gsw;
    else if (rS < 64) wrow = Wk + (size_t)rS * DD + gsw;
    else              wrow = Wv + (size_t)(rS - 64) * DD + gsw;

    floatx4 acc[4][2];
#pragma unroll
    for (int i = 0; i < 4; i++)
#pragma unroll
        for (int j = 0; j < 2; j++) acc[i][j] = (floatx4){0.f, 0.f, 0.f, 0.f};

    // prologue: tile 0 -> buf 0 (barrier drains it)
    gload16(arow, &As[0][tid * 8]);
    gload16(wrow, &Bs[0][tid * 8]);
    __syncthreads();

    int cur = 0;
    for (int t = 0; t < NT; t++) {
        if (t + 1 < NT) {
            const int kn = (t + 1) * BK;
            gload16(arow + kn, &As[cur ^ 1][tid * 8]);
            gload16(wrow + kn, &Bs[cur ^ 1][tid * 8]);
        }
        bf16x8 afr[4], bfr[2];
#pragma unroll
        for (int i = 0; i < 4; i++)
            afr[i] = *(const bf16x8*)&As[cur][(wr * 64 + i * 16 + lo) * BK + qsw * 8];
#pragma unroll
        for (int j = 0; j < 2; j++)
            bfr[j] = *(const bf16x8*)&Bs[cur][(wc * 32 + j * 16 + lo) * BK + qsw * 8];
#pragma unroll
        for (int i = 0; i < 4; i++)
#pragma unroll
            for (int j = 0; j < 2; j++)
                acc[i][j] = __builtin_amdgcn_mfma_f32_16x16x32_bf16(afr[i], bfr[j], acc[i][j], 0, 0, 0);
        __syncthreads();   // guards buf[cur] reuse + drains tile t+1 loads
        cur ^= 1;
    }

#pragma unroll
    for (int i = 0; i < 4; i++)
#pragma unroll
        for (int j = 0; j < 2; j++)
#pragma unroll
            for (int reg = 0; reg < 4; reg++) {
                int row = rowBase + wr * 64 + i * 16 + quad * 4 + reg;  // token
                int c = wc * 32 + j * 16 + lo;                          // 0..127
                float v = acc[i][j][reg];
                if (cb < 8) {
                    QA[(size_t)row * DD + cb * 128 + c] = (bf16_t)(v * SCALEQ);
                } else if (c < 64) {
                    Kp[(size_t)row * HD + c] = (bf16_t)v;
                } else {
                    VpT[((size_t)(row >> 11) * HD + (c - 64)) * SS + (row & (SS - 1))] = (bf16_t)v;
                }
            }
}

__global__ __launch_bounds__(512) void proj_o_b(const bf16_t* __restrict__ AO,
                                                const bf16_t* __restrict__ Wo,
                                                void* __restrict__ Cout,
                                                const int* __restrict__ flagOut) {
    const int fout = *flagOut;

    __shared__ bf16_t As[2][128 * BK];
    __shared__ bf16_t Bs[2][128 * BK];

    const int tid = threadIdx.x;
    const int wave = tid >> 6, lane = tid & 63;
    const int lo = lane & 15, quad = lane >> 4;
    const int qsw = quad ^ (lo & 3);
    const int wr = wave >> 2, wc = wave & 3;
    const int colBase = blockIdx.x * 128;
    const int rowBase = blockIdx.y * 128;

    const int rS = tid >> 2;
    const int gsw = (((tid & 3) ^ (rS & 3)) * 8);

    const bf16_t* arow = AO + (size_t)(rowBase + rS) * DD + gsw;
    const bf16_t* wrow = Wo + (size_t)(colBase + rS) * DD + gsw;

    floatx4 acc[4][2];
#pragma unroll
    for (int i = 0; i < 4; i++)
#pragma unroll
        for (int j = 0; j < 2; j++) acc[i][j] = (floatx4){0.f, 0.f, 0.f, 0.f};

    gload16(arow, &As[0][tid * 8]);
    gload16(wrow, &Bs[0][tid * 8]);
    __syncthreads();

    int cur = 0;
    for (int t = 0; t < NT; t++) {
        if (t + 1 < NT) {
            const int kn = (t + 1) * BK;
            gload16(arow + kn, &As[cur ^ 1][tid * 8]);
            gload16(wrow + kn, &Bs[cur ^ 1][tid * 8]);
        }
        bf16x8 afr[4], bfr[2];
#pragma unroll
        for (int i = 0; i < 4; i++)
            afr[i] = *(const bf16x8*)&As[cur][(wr * 64 + i * 16 + lo) * BK + qsw * 8];
#pragma unroll
        for (int j = 0; j < 2; j++)
            bfr[j] = *(const bf16x8*)&Bs[cur][(wc * 32 + j * 16 + lo) * BK + qsw * 8];
#pragma unroll
        for (int i = 0; i < 4; i++)
#pragma unroll
            for (int j = 0; j < 2; j++)
                acc[i][j] = __builtin_amdgcn_mfma_f32_16x16x32_bf16(afr[i], bfr[j], acc[i][j], 0, 0, 0);
        __syncthreads();
        cur ^= 1;
    }

#pragma unroll
    for (int i = 0; i < 4; i++)
#pragma unroll
        for (int j = 0; j < 2; j++)
#pragma unroll
            for (int reg = 0; reg < 4; reg++) {
                int row = rowBase + wr * 64 + i * 16 + quad * 4 + reg;
                int col = colBase + wc * 32 + j * 16 + lo;
                size_t idx = (size_t)row * DD + col;
                if (fout) ((float*)Cout)[idx] = acc[i][j][reg];
                else      ((bf16_t*)Cout)[idx] = (bf16_t)acc[i][j][reg];
            }
}

// ---------------- OLD dtype-branching projection GEMMs (ws fallback) ----
#define KP 40   // LDS row stride in bf16 elems

__device__ __forceinline__ bf16x4 cvt4(float4 v) {
    bf16x4 o;
    o[0] = (bf16_t)v.x; o[1] = (bf16_t)v.y; o[2] = (bf16_t)v.z; o[3] = (bf16_t)v.w;
    return o;
}

__global__ __launch_bounds__(256) void proj_qkv(const void* __restrict__ X,
                                                const void* __restrict__ Wq,
                                                const void* __restrict__ Wk,
                                                const void* __restrict__ Wv,
                                                bf16_t* __restrict__ QA,
                                                bf16_t* __restrict__ Kp,
                                                bf16_t* __restrict__ VpT,
                                                const int* __restrict__ flag) {
    const int f = *flag;  // 1 => fp32 inputs

    __shared__ bf16_t As[128 * KP];
    __shared__ bf16_t Ws[64 * KP];

    const int tid = threadIdx.x;
    const int wave = tid >> 6, lane = tid & 63;
    const int lo = lane & 15, quad = lane >> 4;
    const int rb = wave * 32;
    const int cb = blockIdx.x;              // 0..17
    const int rowBase = blockIdx.y * 128;

    floatx4 acc[2][4];
#pragma unroll
    for (int i = 0; i < 2; i++)
#pragma unroll
        for (int j = 0; j < 4; j++) acc[i][j] = (floatx4){0.f, 0.f, 0.f, 0.f};

    if (f) {
        const int rA = tid >> 3, sg = tid & 7;
        const float* arow[4];
        const float* wrow[2];
#pragma unroll
        for (int p = 0; p < 4; p++)
            arow[p] = (const float*)X + (size_t)(rowBase + rA + 32 * p) * DD;
#pragma unroll
        for (int p = 0; p < 2; p++) {
            int row = rA + 32 * p;
            if (cb < 16)       wrow[p] = (const float*)Wq + (size_t)(cb * 64 + row) * DD;
            else if (cb == 16) wrow[p] = (const float*)Wk + (size_t)row * DD;
            else               wrow[p] = (const float*)Wv + (size_t)row * DD;
        }
        float4 aR[4], wR[2];
#pragma unroll
        for (int p = 0; p < 4; p++) aR[p] = *(const float4*)(arow[p] + sg * 4);
#pragma unroll
        for (int p = 0; p < 2; p++) wR[p] = *(const float4*)(wrow[p] + sg * 4);

        for (int k0 = 0; k0 < DD; k0 += BK) {
            __syncthreads();
#pragma unroll
            for (int p = 0; p < 4; p++)
                *(bf16x4*)&As[(rA + 32 * p) * KP + sg * 4] = cvt4(aR[p]);
#pragma unroll
            for (int p = 0; p < 2; p++)
                *(bf16x4*)&Ws[(rA + 32 * p) * KP + sg * 4] = cvt4(wR[p]);
            __syncthreads();
            if (k0 + BK < DD) {
#pragma unroll
                for (int p = 0; p < 4; p++) aR[p] = *(const float4*)(arow[p] + k0 + BK + sg * 4);
#pragma unroll
                for (int p = 0; p < 2; p++) wR[p] = *(const float4*)(wrow[p] + k0 + BK + sg * 4);
            }
            bf16x8 afr[2], bfr[4];
#pragma unroll
            for (int i = 0; i < 2; i++)
                afr[i] = *(const bf16x8*)&As[(rb + i * 16 + lo) * KP + quad * 8];
#pragma unroll
            for (int j = 0; j < 4; j++)
                bfr[j] = *(const bf16x8*)&Ws[(j * 16 + lo) * KP + quad * 8];
#pragma unroll
            for (int i = 0; i < 2; i++)
#pragma unroll
                for (int j = 0; j < 4; j++)
                    acc[i][j] = __builtin_amdgcn_mfma_f32_16x16x32_bf16(afr[i], bfr[j], acc[i][j], 0, 0, 0);
        }
    } else {
        const int rA = tid >> 2, sg = tid & 3;
        const bf16_t* arow[2];
        const bf16_t* wrow;
#pragma unroll
        for (int p = 0; p < 2; p++)
            arow[p] = (const bf16_t*)X + (size_t)(rowBase + rA + 64 * p) * DD;
        if (cb < 16)       wrow = (const bf16_t*)Wq + (size_t)(cb * 64 + rA) * DD;
        else if (cb == 16) wrow = (const bf16_t*)Wk + (size_t)rA * DD;
        else               wrow = (const bf16_t*)Wv + (size_t)rA * DD;
        bf16x8 aR[2], wR;
#pragma unroll
        for (int p = 0; p < 2; p++) aR[p] = *(const bf16x8*)(arow[p] + sg * 8);
        wR = *(const bf16x8*)(wrow + sg * 8);

        for (int k0 = 0; k0 < DD; k0 += BK) {
            __syncthreads();
#pragma unroll
            for (int p = 0; p < 2; p++)
                *(bf16x8*)&As[(rA + 64 * p) * KP + sg * 8] = aR[p];
            *(bf16x8*)&Ws[rA * KP + sg * 8] = wR;
            __syncthreads();
            if (k0 + BK < DD) {
#pragma unroll
                for (int p = 0; p < 2; p++) aR[p] = *(const bf16x8*)(arow[p] + k0 + BK + sg * 8);
                wR = *(const bf16x8*)(wrow + k0 + BK + sg * 8);
            }
            bf16x8 afr[2], bfr[4];
#pragma unroll
            for (int i = 0; i < 2; i++)
                afr[i] = *(const bf16x8*)&As[(rb + i * 16 + lo) * KP + quad * 8];
#pragma unroll
            for (int j = 0; j < 4; j++)
                bfr[j] = *(const bf16x8*)&Ws[(j * 16 + lo) * KP + quad * 8];
#pragma unroll
            for (int i = 0; i < 2; i++)
#pragma unroll
                for (int j = 0; j < 4; j++)
                    acc[i][j] = __builtin_amdgcn_mfma_f32_16x16x32_bf16(afr[i], bfr[j], acc[i][j], 0, 0, 0);
        }
    }

#pragma unroll
    for (int i = 0; i < 2; i++)
#pragma unroll
        for (int j = 0; j < 4; j++)
#pragma unroll
            for (int reg = 0; reg < 4; reg++) {
                int row = rowBase + rb + i * 16 + quad * 4 + reg;
                int col = j * 16 + lo;
                if (cb < 16) {
                    QA[(size_t)row * DD + cb * 64 + col] = (bf16_t)(acc[i][j][reg] * SCALEQ);
                } else if (cb == 16) {
                    Kp[(size_t)row * HD + col] = (bf16_t)acc[i][j][reg];
                } else {
                    VpT[((size_t)(row >> 11) * HD + col) * SS + (row & (SS - 1))] =
                        (bf16_t)acc[i][j][reg];
                }
            }
}

__global__ __launch_bounds__(256) void proj_o(const bf16_t* __restrict__ AO,
                                              const void* __restrict__ Wo,
                                              void* __restrict__ Cout,
                                              const int* __restrict__ flagW,
                                              const int* __restrict__ flagOut) {
    const int f = *flagW;
    const int fout = *flagOut;

    __shared__ bf16_t As[128 * KP];
    __shared__ bf16_t Ws[64 * KP];

    const int tid = threadIdx.x;
    const int wave = tid >> 6, lane = tid & 63;
    const int lo = lane & 15, quad = lane >> 4;
    const int rb = wave * 32;
    const int colBase = blockIdx.x * 64;
    const int rowBase = blockIdx.y * 128;

    floatx4 acc[2][4];
#pragma unroll
    for (int i = 0; i < 2; i++)
#pragma unroll
        for (int j = 0; j < 4; j++) acc[i][j] = (floatx4){0.f, 0.f, 0.f, 0.f};

    const int rA2 = tid >> 2, sgA = tid & 3;
    const bf16_t* arow[2] = {AO + (size_t)(rowBase + rA2) * DD,
                             AO + (size_t)(rowBase + rA2 + 64) * DD};
    bf16x8 aR[2];
#pragma unroll
    for (int p = 0; p < 2; p++) aR[p] = *(const bf16x8*)(arow[p] + sgA * 8);

    if (f) {
        const int rW = tid >> 3, sgW = tid & 7;
        const float* wrow[2];
#pragma unroll
        for (int p = 0; p < 2; p++)
            wrow[p] = (const float*)Wo + (size_t)(colBase + rW + 32 * p) * DD;
        float4 wR[2];
#pragma unroll
        for (int p = 0; p < 2; p++) wR[p] = *(const float4*)(wrow[p] + sgW * 4);

        for (int k0 = 0; k0 < DD; k0 += BK) {
            __syncthreads();
#pragma unroll
            for (int p = 0; p < 2; p++)
                *(bf16x8*)&As[(rA2 + 64 * p) * KP + sgA * 8] = aR[p];
#pragma unroll
            for (int p = 0; p < 2; p++)
                *(bf16x4*)&Ws[(rW + 32 * p) * KP + sgW * 4] = cvt4(wR[p]);
            __syncthreads();
            if (k0 + BK < DD) {
#pragma unroll
                for (int p = 0; p < 2; p++) aR[p] = *(const bf16x8*)(arow[p] + k0 + BK + sgA * 8);
#pragma unroll
                for (int p = 0; p < 2; p++) wR[p] = *(const float4*)(wrow[p] + k0 + BK + sgW * 4);
            }
            bf16x8 afr[2], bfr[4];
#pragma unroll
            for (int i = 0; i < 2; i++)
                afr[i] = *(const bf16x8*)&As[(rb + i * 16 + lo) * KP + quad * 8];
#pragma unroll
            for (int j = 0; j < 4; j++)
                bfr[j] = *(const bf16x8*)&Ws[(j * 16 + lo) * KP + quad * 8];
#pragma unroll
            for (int i = 0; i < 2; i++)
#pragma unroll
                for (int j = 0; j < 4; j++)
                    acc[i][j] = __builtin_amdgcn_mfma_f32_16x16x32_bf16(afr[i], bfr[j], acc[i][j], 0, 0, 0);
        }
    } else {
        const bf16_t* wrow = (const bf16_t*)Wo + (size_t)(colBase + rA2) * DD;
        bf16x8 wR = *(const bf16x8*)(wrow + sgA * 8);

        for (int k0 = 0; k0 < DD; k0 += BK) {
            __syncthreads();
#pragma unroll
            for (int p = 0; p < 2; p++)
                *(bf16x8*)&As[(rA2 + 64 * p) * KP + sgA * 8] = aR[p];
            *(bf16x8*)&Ws[rA2 * KP + sgA * 8] = wR;
            __syncthreads();
            if (k0 + BK < DD) {
#pragma unroll
                for (int p = 0; p < 2; p++) aR[p] = *(const bf16x8*)(arow[p] + k0 + BK + sgA * 8);
                wR = *(const bf16x8*)(wrow + k0 + BK + sgA * 8);
            }
            bf16x8 afr[2], bfr[4];
#pragma unroll
            for (int i = 0; i < 2; i++)
                afr[i] = *(const bf16x8*)&As[(rb + i * 16 + lo) * KP + quad * 8];
#pragma unroll
            for (int j = 0; j < 4; j++)
                bfr[j] = *(const bf16x8*)&Ws[(j * 16 + lo) * KP + quad * 8];
#pragma unroll
            for (int i = 0; i < 2; i++)
#pragma unroll
                for (int j = 0; j < 4; j++)
                    acc[i][j] = __builtin_amdgcn_mfma_f32_16x16x32_bf16(afr[i], bfr[j], acc[i][j], 0, 0, 0);
        }
    }

#pragma unroll
    for (int i = 0; i < 2; i++)
#pragma unroll
        for (int j = 0; j < 4; j++)
#pragma unroll
            for (int reg = 0; reg < 4; reg++) {
                int row = rowBase + rb + i * 16 + quad * 4 + reg;
                int col = colBase + j * 16 + lo;
                size_t idx = (size_t)row * DD + col;
                if (fout) ((float*)Cout)[idx] = acc[i][j][reg];
                else      ((bf16_t*)Cout)[idx] = (bf16_t)acc[i][j][reg];
            }
}

// ---------------- barrier-free MFMA flash attention, balanced key-split ----
// 512-thread blocks (8 waves), pair (x, 63-x): 65 key-tiles per block by
// construction; waves assigned proportionally (worst ~10 tiles). Defer-max
// softmax (shuffle-free common case). __launch_bounds__(512, 4): 128-VGPR
// budget. PROVEN: (512,8)->64-reg and (512,6)->85-reg caps BOTH spill
// catastrophically (0.6-1.5 GB scratch traffic); the wave's live set needs
// the full 128-reg bin. Do not lower this cap again.
#define PSTR 40
#define DMTHR 8.0f    // defer-max threshold (exp2 domain)

__global__ __launch_bounds__(512, 4) void attn_mfma(const bf16_t* Q,
                                                    const bf16_t* __restrict__ K,
                                                    const bf16_t* __restrict__ Vt,
                                                    bf16_t* O) {
    const int h = blockIdx.y, b = blockIdx.z;
    const int tid = threadIdx.x;
    const int wq = tid >> 6, lane = tid & 63;
    const int lo = lane & 15, quad = lane >> 4;
    const int x = blockIdx.x;           // 0..31 -> pair (x, 63-x)

    // --- proportional wave->q-tile assignment (minimize max wave tiles) ---
    const int nA = x + 1;               // key-tiles for qt = x (pair total 65)
    int na = 1, bestc = 0x7fffffff;
#pragma unroll
    for (int a = 1; a <= 7; ++a) {
        int cA = (nA + a - 1) / a;
        int cB = (65 - nA + (7 - a)) / (8 - a);
        int c = cA > cB ? cA : cB;
        if (c < bestc) { bestc = c; na = a; }
    }
    int qt, pos, gs;
    if (wq < na) { qt = x;      pos = wq;      gs = na; }
    else         { qt = 63 - x; pos = wq - na; gs = 8 - na; }
    const int q0 = qt * 32;
    const int n = qt + 1;               // total key-tiles for this q-tile
    const int itS = (n * pos) / gs;
    const int itE = (n * (pos + 1)) / gs;

    // --- LDS: P staging (per-wave, loop phase) unions merge buffers ---
    __shared__ __align__(16) char smem[4 * 32 * 64 * 4];  // 32768 B
    __shared__ float MrgML[4][2][2][16];                  // [buf][s][m/l][lo]
    bf16_t* Pw = (bf16_t*)smem + wq * (32 * PSTR);        // 8 x 2560 B = 20480 B
    float (*MrgO)[32 * 64] = (float (*)[32 * 64])smem;    // 4 bufs x 8 KB

    // Q frags (B operand: n=q, k=dim); Q already scaled by (1/8)*log2(e)
    bf16x8 qf[2][2];
#pragma unroll
    for (int s = 0; s < 2; s++)
#pragma unroll
        for (int hf = 0; hf < 2; hf++)
            qf[s][hf] = *(const bf16x8*)(Q + ((size_t)(b * SS + q0 + s * 16 + lo)) * DD +
                                         h * HD + hf * 32 + quad * 8);

    floatx4 Oacc[2][4];
    float m_i[2], l_ln[2];   // m: column-consistent running max; l: LANE-partial
#pragma unroll
    for (int s = 0; s < 2; s++) {
#pragma unroll
        for (int dt = 0; dt < 4; dt++) Oacc[s][dt] = (floatx4){0.f, 0.f, 0.f, 0.f};
        m_i[s] = -1e30f; l_ln[s] = 0.f;
    }

    const bf16_t* Kb = K + (size_t)b * SS * HD;
    const bf16_t* Vb = Vt + (size_t)b * HD * SS;

    if (itS < itE) {
        // preload K tile itS
        bf16x8 kf[2][2];
#pragma unroll
        for (int kt = 0; kt < 2; kt++)
#pragma unroll
            for (int hf = 0; hf < 2; hf++)
                kf[kt][hf] = *(const bf16x8*)(Kb + (size_t)(itS * 32 + kt * 16 + lo) * HD +
                                              hf * 32 + quad * 8);

        for (int it = itS; it < itE; it++) {
            const int t0 = it * 32;

            bf16x8 vf[4];
#pragma unroll
            for (int dt = 0; dt < 4; dt++)
                vf[dt] = *(const bf16x8*)(Vb + (size_t)(dt * 16 + lo) * SS + t0 + quad * 8);

            bf16x8 kn[2][2];
            if (it + 1 < itE) {
#pragma unroll
                for (int kt = 0; kt < 2; kt++)
#pragma unroll
                    for (int hf = 0; hf < 2; hf++)
                        kn[kt][hf] = *(const bf16x8*)(Kb + (size_t)(t0 + 32 + kt * 16 + lo) * HD +
                                                      hf * 32 + quad * 8);
            }

            // S^T = K.Q^T  (already in exp2 domain via pre-scaled Q)
            floatx4 st[2][2];
#pragma unroll
            for (int s = 0; s < 2; s++)
#pragma unroll
                for (int kt = 0; kt < 2; kt++) {
                    floatx4 z = (floatx4){0.f, 0.f, 0.f, 0.f};
                    z = __builtin_amdgcn_mfma_f32_16x16x32_bf16(kf[kt][0], qf[s][0], z, 0, 0, 0);
                    z = __builtin_amdgcn_mfma_f32_16x16x32_bf16(kf[kt][1], qf[s][1], z, 0, 0, 0);
                    st[s][kt] = z;
                }

            if (it == qt) {  // diagonal tile (always last pos of the group)
#pragma unroll
                for (int s = 0; s < 2; s++) {
                    int q = q0 + s * 16 + lo;
#pragma unroll
                    for (int kt = 0; kt < 2; kt++)
#pragma unroll
                        for (int reg = 0; reg < 4; reg++)
                            if (t0 + kt * 16 + quad * 4 + reg > q) st[s][kt][reg] = -1e30f;
                }
            }

            // defer-max online softmax: shuffle-free in the common case
#pragma unroll
            for (int s = 0; s < 2; s++) {
                float lm = fmaxf(fmaxf(fmaxf(st[s][0][0], st[s][0][1]), fmaxf(st[s][0][2], st[s][0][3])),
                                 fmaxf(fmaxf(st[s][1][0], st[s][1][1]), fmaxf(st[s][1][2], st[s][1][3])));
                if (__any(lm > m_i[s] + DMTHR)) {
                    float mx = fmaxf(lm, __shfl_xor(lm, 16));
                    mx = fmaxf(mx, __shfl_xor(mx, 32));
                    float mn = fmaxf(m_i[s], mx);
                    float al = exp2f(m_i[s] - mn);
                    m_i[s] = mn;
                    l_ln[s] *= al;
#pragma unroll
                    for (int dt = 0; dt < 4; dt++) Oacc[s][dt] *= al;
                }
                float p[2][4];
#pragma unroll
                for (int kt = 0; kt < 2; kt++)
#pragma unroll
                    for (int reg = 0; reg < 4; reg++)
                        p[kt][reg] = exp2f(st[s][kt][reg] - m_i[s]);
                l_ln[s] += ((p[0][0] + p[0][1]) + (p[0][2] + p[0][3])) +
                           ((p[1][0] + p[1][1]) + (p[1][2] + p[1][3]));
#pragma unroll
                for (int kt = 0; kt < 2; kt++) {
                    bf16x4 pk;
#pragma unroll
                    for (int reg = 0; reg < 4; reg++) pk[reg] = (bf16_t)p[kt][reg];
                    *(bf16x4*)&Pw[(s * 16 + lo) * PSTR + kt * 16 + quad * 4] = pk;
                }
            }

            asm volatile("s_waitcnt lgkmcnt(0)" ::: "memory");

            // O^T += V^T . P^T
            bf16x8 pb[2];
#pragma unroll
            for (int s = 0; s < 2; s++)
                pb[s] = *(const bf16x8*)&Pw[(s * 16 + lo) * PSTR + quad * 8];
#pragma unroll
            for (int s = 0; s < 2; s++)
#pragma unroll
                for (int dt = 0; dt < 4; dt++)
                    Oacc[s][dt] = __builtin_amdgcn_mfma_f32_16x16x32_bf16(vf[dt], pb[s], Oacc[s][dt], 0, 0, 0);

#pragma unroll
            for (int kt = 0; kt < 2; kt++)
#pragma unroll
                for (int hf = 0; hf < 2; hf++) kf[kt][hf] = kn[kt][hf];
        }
    }

    // ---- finalize lane-partial l into column-consistent l_i ----
    float l_i[2];
#pragma unroll
    for (int s = 0; s < 2; s++) {
        float l = l_ln[s];
        l += __shfl_xor(l, 16);
        l += __shfl_xor(l, 32);
        l_i[s] = l;
    }

    // ---- binary-tree merge within each wave group (flash merge algebra) ----
    for (int step = 1; step < 8; step <<= 1) {
        const bool pub = (pos & (2 * step - 1)) == step;
        const bool cmb = ((pos & (2 * step - 1)) == 0) && (pos + step < gs);
        __syncthreads();   // previous round's reads (and P-staging use) done
        if (pub) {
            float* Ob = MrgO[wq >> 1];
#pragma unroll
            for (int s = 0; s < 2; s++) {
#pragma unroll
                for (int dt = 0; dt < 4; dt++)
#pragma unroll
                    for (int reg = 0; reg < 4; reg++)
                        Ob[(s * 16 + dt * 4 + reg) * 64 + lane] = Oacc[s][dt][reg];
                if (quad == 0) {
                    MrgML[wq >> 1][s][0][lo] = m_i[s];
                    MrgML[wq >> 1][s][1][lo] = l_i[s];
                }
            }
        }
        __syncthreads();
        if (cmb) {
            const int bu = (wq + step) >> 1;
            const float* Ob = MrgO[bu];
#pragma unroll
            for (int s = 0; s < 2; s++) {
                float m1 = MrgML[bu][s][0][lo];
                float l1 = MrgML[bu][s][1][lo];
                float mm = fmaxf(m_i[s], m1);
                float a0 = exp2f(m_i[s] - mm);
                float a1 = exp2f(m1 - mm);
                m_i[s] = mm;
                l_i[s] = l_i[s] * a0 + l1 * a1;
#pragma unroll
                for (int dt = 0; dt < 4; dt++)
#pragma unroll
                    for (int reg = 0; reg < 4; reg++)
                        Oacc[s][dt][reg] = Oacc[s][dt][reg] * a0 +
                                           Ob[(s * 16 + dt * 4 + reg) * 64 + lane] * a1;
            }
        }
    }

    // ---- group leaders (pos==0: waves 0 and na) finalize + store ----
    if (pos == 0) {
#pragma unroll
        for (int s = 0; s < 2; s++) {
            float linv = 1.f / l_i[s];
            bf16_t* Orow = O + ((size_t)(b * SS + q0 + s * 16 + lo)) * DD + h * HD;
#pragma unroll
            for (int dt = 0; dt < 4; dt++) {
                bf16x4 ov;
#pragma unroll
                for (int reg = 0; reg < 4; reg++)
                    ov[reg] = (bf16_t)(Oacc[s][dt][reg] * linv);
                *(bf16x4*)&Orow[dt * 16 + quad * 4] = ov;
            }
        }
    }
}

// ---------------- launch ----------------
extern "C" void kernel_launch(void* const* d_in, const int* in_sizes, int n_in,
                              void* d_out, int out_size, void* d_ws, size_t ws_size,
                              hipStream_t stream) {
    const void* x  = d_in[0];
    const void* Wq = d_in[1];
    const void* Wk = d_in[2];
    const void* Wv = d_in[3];
    const void* Wo = d_in[4];
    // d_in[5] = causal mask — known tril, handled analytically in attn_mfma.

    // Workspace layout:
    // [flag 2xint, 256B] | QA bf16[4096,1024] | Kp bf16[4096,64] |
    // VpT bf16[2][64][2048] | Xb bf16[4096,1024] | Wqb bf16[1024,1024] |
    // Wkb bf16[64,1024] | Wvb bf16[64,1024] | Wob bf16[1024,1024]
    char* ws = (char*)d_ws;
    int* flag = (int*)ws;
    bf16_t* QA  = (bf16_t*)(ws + 256);
    bf16_t* Kp  = QA + (size_t)MM * DD;
    bf16_t* VpT = Kp + (size_t)MM * HD;
    bf16_t* Xb  = VpT + (size_t)BB * HD * SS;
    bf16_t* Wqb = Xb + (size_t)MM * DD;
    bf16_t* Wkb = Wqb + (size_t)DD * DD;
    bf16_t* Wvb = Wkb + (size_t)HD * DD;
    bf16_t* Wob = Wvb + (size_t)HD * DD;
    size_t need = (size_t)((char*)(Wob + (size_t)DD * DD) - ws);

    detect_dtype<<<1, 64, 0, stream>>>((const unsigned int*)x, flag);

    if (ws_size >= need) {
        // Convert all operands to bf16 once; projections run the fat-tile
        // bf16-only path (128x128, 512 thr, global_load_lds staging).
        conv_all<<<dim3(1024), dim3(256), 0, stream>>>(x, Wq, Wk, Wv, Wo,
                                                       Xb, Wqb, Wkb, Wvb, Wob, flag);
        proj_qkv_b<<<dim3(9, MM / 128), dim3(512), 0, stream>>>(Xb, Wqb, Wkb, Wvb,
                                                                QA, Kp, VpT);
        attn_mfma<<<dim3(32, NH, BB), dim3(512), 0, stream>>>(QA, Kp, VpT, QA);
        proj_o_b<<<dim3(8, MM / 128), dim3(512), 0, stream>>>(QA, Wob, d_out, flag);
    } else {
        // Fallback: original direct-from-input path.
        proj_qkv<<<dim3(18, MM / 128), dim3(256), 0, stream>>>(x, Wq, Wk, Wv,
                                                               QA, Kp, VpT, flag);
        attn_mfma<<<dim3(32, NH, BB), dim3(512), 0, stream>>>(QA, Kp, VpT, QA);
        proj_o<<<dim3(16, MM / 128), dim3(256), 0, stream>>>(QA, Wo, d_out,
                                                             flag, flag);
    }
}

// Round 9
// 208.708 us; speedup vs baseline: 1.0593x; 1.0593x over previous
//
#include <hip/hip_runtime.h>
#include <hip/hip_bf16.h>
#include <math.h>

// Problem constants (MultiQueryAttention: B=2, S=2048, D=1024, H=16, hd=64)
#define BB 2
#define SS 2048
#define DD 1024
#define NH 16
#define HD 64
#define MM (BB * SS)  // 4096 tokens

#define BK 64            // GEMM k-step (doubled from 32: halves barrier count)

typedef __hip_bfloat16 bf16;
typedef __bf16 bf16_t;
typedef __attribute__((ext_vector_type(8))) __bf16 bf16x8;
typedef __attribute__((ext_vector_type(4))) __bf16 bf16x4;
typedef __attribute__((ext_vector_type(4))) float floatx4;

// (1/sqrt(64)) * log2(e): folded into Q at projection time so QK^T scores
// come out directly in the exp2 domain.
#define SCALEQ 0.18033688011112042f

// ---------------- runtime dtype detection (parallel) ----------------
// flag[0]==1 -> external tensors are fp32; flag[0]==0 -> bf16.
// flag[1] is always 0 (a "bf16" flag for the converted-input path).
__global__ void detect_dtype(const unsigned int* __restrict__ x, int* __restrict__ flag) {
    const int tid = threadIdx.x;  // 64 lanes
    int good = 0;
    for (int i = tid; i < 256; i += 64) {
        unsigned int bits = (x[i] & 0xFFFFu) << 16;
        float v = __uint_as_float(bits);
        float av = fabsf(v);
        if (av == 0.f || (av >= 9.5367431640625e-7f && av <= 64.f)) good++;
    }
#pragma unroll
    for (int s = 1; s < 64; s <<= 1) good += __shfl_xor(good, s);
    if (tid == 0) { flag[0] = (good >= 240) ? 0 : 1; flag[1] = 0; }
}

// ---------------- bulk fp32->bf16 conversion (or bf16 passthrough) -------
__device__ __forceinline__ void conv_seg(const void* __restrict__ in,
                                         bf16_t* __restrict__ out,
                                         int n, int f, int tid, int T) {
    if (f) {
        const float* p = (const float*)in;
        for (int i = tid * 8; i < n; i += T * 8) {
            float4 a = *(const float4*)(p + i);
            float4 b = *(const float4*)(p + i + 4);
            bf16x8 o;
            o[0] = (bf16_t)a.x; o[1] = (bf16_t)a.y; o[2] = (bf16_t)a.z; o[3] = (bf16_t)a.w;
            o[4] = (bf16_t)b.x; o[5] = (bf16_t)b.y; o[6] = (bf16_t)b.z; o[7] = (bf16_t)b.w;
            *(bf16x8*)(out + i) = o;
        }
    } else {
        const bf16_t* p = (const bf16_t*)in;
        for (int i = tid * 8; i < n; i += T * 8)
            *(bf16x8*)(out + i) = *(const bf16x8*)(p + i);
    }
}

__global__ __launch_bounds__(256) void conv_all(const void* __restrict__ x,
                                                const void* __restrict__ wq,
                                                const void* __restrict__ wk,
                                                const void* __restrict__ wv,
                                                const void* __restrict__ wo,
                                                bf16_t* __restrict__ xb,
                                                bf16_t* __restrict__ wqb,
                                                bf16_t* __restrict__ wkb,
                                                bf16_t* __restrict__ wvb,
                                                bf16_t* __restrict__ wob,
                                                const int* __restrict__ flag) {
    const int f = *flag;
    const int tid = blockIdx.x * blockDim.x + threadIdx.x;
    const int T = gridDim.x * blockDim.x;
    conv_seg(x, xb, MM * DD, f, tid, T);
    conv_seg(wq, wqb, DD * DD, f, tid, T);
    conv_seg(wk, wkb, HD * DD, f, tid, T);
    conv_seg(wv, wvb, HD * DD, f, tid, T);
    conv_seg(wo, wob, DD * DD, f, tid, T);
}

// ------- 128x128-tile bf16 projection GEMMs (512 thr, BK=64, depth-2) ----
// 8 waves in 2x4; each wave owns 64x32 with acc[4][2] and 16 MFMA/k-step
// (2 kk-substeps of K=32). BK=64 halves the barrier count vs BK=32 and
// doubles MFMA per staged phase. Depth-2 NAMED register prefetch (loads for
// tile t+2 issue during tile t) gives ~2 k-steps of latency cover — PROVEN
// better than 1-deep global_load_lds (R8: the vmcnt(0) barrier drain caps
// gload_lds at 1-deep; regressed 11 us). KP2=72 row stride: 144 B = 36
// banks == 4 (mod 32) -> 64-lane b128 reads spread uniformly 8 lanes per
// 4-bank group = conflict-free. Grid is TRANSPOSED (row-tile fastest):
// consecutive block ids share one weight panel and spread X row-panels
// across XCDs -> W panel L2-resident per XCD (T1).
#define KP2 72

__global__ __launch_bounds__(512) void proj_qkv_b(const bf16_t* __restrict__ X,
                                                  const bf16_t* __restrict__ Wq,
                                                  const bf16_t* __restrict__ Wk,
                                                  const bf16_t* __restrict__ Wv,
                                                  bf16_t* __restrict__ QA,
                                                  bf16_t* __restrict__ Kp,
                                                  bf16_t* __restrict__ VpT) {
    __shared__ bf16_t As[128 * KP2];
    __shared__ bf16_t Bs[128 * KP2];

    const int tid = threadIdx.x;
    const int wave = tid >> 6, lane = tid & 63;
    const int lo = lane & 15, quad = lane >> 4;
    const int wr = wave >> 2, wc = wave & 3;       // 2x4 wave grid
    const int rowBase = blockIdx.x * 128;          // row tile (fastest dim)
    const int cb = blockIdx.y;                     // 0..8 (8 => K|V fused)

    // staging: thread covers row rS, 16 cols at c16; 32B/operand/thread
    const int rS = tid >> 2;           // 0..127
    const int c16 = (tid & 3) * 16;    // 0,16,32,48

    const bf16_t* arow = X + (size_t)(rowBase + rS) * DD + c16;
    const bf16_t* wrow;
    if (cb < 8)       wrow = Wq + (size_t)(cb * 128 + rS) * DD + c16;
    else if (rS < 64) wrow = Wk + (size_t)rS * DD + c16;
    else              wrow = Wv + (size_t)(rS - 64) * DD + c16;

    floatx4 acc[4][2];
#pragma unroll
    for (int i = 0; i < 4; i++)
#pragma unroll
        for (int j = 0; j < 2; j++) acc[i][j] = (floatx4){0.f, 0.f, 0.f, 0.f};

    // depth-2 prefetch: two NAMED register sets (no runtime indexing)
    bf16x8 aR0[2], bR0[2], aR1[2], bR1[2];
#pragma unroll
    for (int p = 0; p < 2; p++) {
        aR0[p] = *(const bf16x8*)(arow + p * 8);
        bR0[p] = *(const bf16x8*)(wrow + p * 8);
        aR1[p] = *(const bf16x8*)(arow + BK + p * 8);
        bR1[p] = *(const bf16x8*)(wrow + BK + p * 8);
    }

    for (int k0 = 0; k0 < DD; k0 += 2 * BK) {
        // ---- sub-step A: tile k0 (set 0) ----
        __syncthreads();
#pragma unroll
        for (int p = 0; p < 2; p++) {
            *(bf16x8*)&As[rS * KP2 + c16 + p * 8] = aR0[p];
            *(bf16x8*)&Bs[rS * KP2 + c16 + p * 8] = bR0[p];
        }
        __syncthreads();
        if (k0 + 2 * BK < DD) {
#pragma unroll
            for (int p = 0; p < 2; p++) {
                aR0[p] = *(const bf16x8*)(arow + k0 + 2 * BK + p * 8);
                bR0[p] = *(const bf16x8*)(wrow + k0 + 2 * BK + p * 8);
            }
        }
#pragma unroll
        for (int kk = 0; kk < 2; kk++) {
            bf16x8 afr[4], bfr[2];
#pragma unroll
            for (int i = 0; i < 4; i++)
                afr[i] = *(const bf16x8*)&As[(wr * 64 + i * 16 + lo) * KP2 + kk * 32 + quad * 8];
#pragma unroll
            for (int j = 0; j < 2; j++)
                bfr[j] = *(const bf16x8*)&Bs[(wc * 32 + j * 16 + lo) * KP2 + kk * 32 + quad * 8];
#pragma unroll
            for (int i = 0; i < 4; i++)
#pragma unroll
                for (int j = 0; j < 2; j++)
                    acc[i][j] = __builtin_amdgcn_mfma_f32_16x16x32_bf16(afr[i], bfr[j], acc[i][j], 0, 0, 0);
        }
        // ---- sub-step B: tile k0+BK (set 1) ----
        __syncthreads();
#pragma unroll
        for (int p = 0; p < 2; p++) {
            *(bf16x8*)&As[rS * KP2 + c16 + p * 8] = aR1[p];
            *(bf16x8*)&Bs[rS * KP2 + c16 + p * 8] = bR1[p];
        }
        __syncthreads();
        if (k0 + 3 * BK < DD) {
#pragma unroll
            for (int p = 0; p < 2; p++) {
                aR1[p] = *(const bf16x8*)(arow + k0 + 3 * BK + p * 8);
                bR1[p] = *(const bf16x8*)(wrow + k0 + 3 * BK + p * 8);
            }
        }
#pragma unroll
        for (int kk = 0; kk < 2; kk++) {
            bf16x8 afr[4], bfr[2];
#pragma unroll
            for (int i = 0; i < 4; i++)
                afr[i] = *(const bf16x8*)&As[(wr * 64 + i * 16 + lo) * KP2 + kk * 32 + quad * 8];
#pragma unroll
            for (int j = 0; j < 2; j++)
                bfr[j] = *(const bf16x8*)&Bs[(wc * 32 + j * 16 + lo) * KP2 + kk * 32 + quad * 8];
#pragma unroll
            for (int i = 0; i < 4; i++)
#pragma unroll
                for (int j = 0; j < 2; j++)
                    acc[i][j] = __builtin_amdgcn_mfma_f32_16x16x32_bf16(afr[i], bfr[j], acc[i][j], 0, 0, 0);
        }
    }

#pragma unroll
    for (int i = 0; i < 4; i++)
#pragma unroll
        for (int j = 0; j < 2; j++)
#pragma unroll
            for (int reg = 0; reg < 4; reg++) {
                int row = rowBase + wr * 64 + i * 16 + quad * 4 + reg;  // token
                int c = wc * 32 + j * 16 + lo;                          // 0..127
                float v = acc[i][j][reg];
                if (cb < 8) {
                    QA[(size_t)row * DD + cb * 128 + c] = (bf16_t)(v * SCALEQ);
                } else if (c < 64) {
                    Kp[(size_t)row * HD + c] = (bf16_t)v;
                } else {
                    VpT[((size_t)(row >> 11) * HD + (c - 64)) * SS + (row & (SS - 1))] = (bf16_t)v;
                }
            }
}

__global__ __launch_bounds__(512) void proj_o_b(const bf16_t* __restrict__ AO,
                                                const bf16_t* __restrict__ Wo,
                                                void* __restrict__ Cout,
                                                const int* __restrict__ flagOut) {
    const int fout = *flagOut;

    __shared__ bf16_t As[128 * KP2];
    __shared__ bf16_t Bs[128 * KP2];

    const int tid = threadIdx.x;
    const int wave = tid >> 6, lane = tid & 63;
    const int lo = lane & 15, quad = lane >> 4;
    const int wr = wave >> 2, wc = wave & 3;
    const int rowBase = blockIdx.x * 128;          // row tile (fastest dim)
    const int colBase = blockIdx.y * 128;

    const int rS = tid >> 2;
    const int c16 = (tid & 3) * 16;

    const bf16_t* arow = AO + (size_t)(rowBase + rS) * DD + c16;
    const bf16_t* wrow = Wo + (size_t)(colBase + rS) * DD + c16;

    floatx4 acc[4][2];
#pragma unroll
    for (int i = 0; i < 4; i++)
#pragma unroll
        for (int j = 0; j < 2; j++) acc[i][j] = (floatx4){0.f, 0.f, 0.f, 0.f};

    bf16x8 aR0[2], bR0[2], aR1[2], bR1[2];
#pragma unroll
    for (int p = 0; p < 2; p++) {
        aR0[p] = *(const bf16x8*)(arow + p * 8);
        bR0[p] = *(const bf16x8*)(wrow + p * 8);
        aR1[p] = *(const bf16x8*)(arow + BK + p * 8);
        bR1[p] = *(const bf16x8*)(wrow + BK + p * 8);
    }

    for (int k0 = 0; k0 < DD; k0 += 2 * BK) {
        __syncthreads();
#pragma unroll
        for (int p = 0; p < 2; p++) {
            *(bf16x8*)&As[rS * KP2 + c16 + p * 8] = aR0[p];
            *(bf16x8*)&Bs[rS * KP2 + c16 + p * 8] = bR0[p];
        }
        __syncthreads();
        if (k0 + 2 * BK < DD) {
#pragma unroll
            for (int p = 0; p < 2; p++) {
                aR0[p] = *(const bf16x8*)(arow + k0 + 2 * BK + p * 8);
                bR0[p] = *(const bf16x8*)(wrow + k0 + 2 * BK + p * 8);
            }
        }
#pragma unroll
        for (int kk = 0; kk < 2; kk++) {
            bf16x8 afr[4], bfr[2];
#pragma unroll
            for (int i = 0; i < 4; i++)
                afr[i] = *(const bf16x8*)&As[(wr * 64 + i * 16 + lo) * KP2 + kk * 32 + quad * 8];
#pragma unroll
            for (int j = 0; j < 2; j++)
                bfr[j] = *(const bf16x8*)&Bs[(wc * 32 + j * 16 + lo) * KP2 + kk * 32 + quad * 8];
#pragma unroll
            for (int i = 0; i < 4; i++)
#pragma unroll
                for (int j = 0; j < 2; j++)
                    acc[i][j] = __builtin_amdgcn_mfma_f32_16x16x32_bf16(afr[i], bfr[j], acc[i][j], 0, 0, 0);
        }
        __syncthreads();
#pragma unroll
        for (int p = 0; p < 2; p++) {
            *(bf16x8*)&As[rS * KP2 + c16 + p * 8] = aR1[p];
            *(bf16x8*)&Bs[rS * KP2 + c16 + p * 8] = bR1[p];
        }
        __syncthreads();
        if (k0 + 3 * BK < DD) {
#pragma unroll
            for (int p = 0; p < 2; p++) {
                aR1[p] = *(const bf16x8*)(arow + k0 + 3 * BK + p * 8);
                bR1[p] = *(const bf16x8*)(wrow + k0 + 3 * BK + p * 8);
            }
        }
#pragma unroll
        for (int kk = 0; kk < 2; kk++) {
            bf16x8 afr[4], bfr[2];
#pragma unroll
            for (int i = 0; i < 4; i++)
                afr[i] = *(const bf16x8*)&As[(wr * 64 + i * 16 + lo) * KP2 + kk * 32 + quad * 8];
#pragma unroll
            for (int j = 0; j < 2; j++)
                bfr[j] = *(const bf16x8*)&Bs[(wc * 32 + j * 16 + lo) * KP2 + kk * 32 + quad * 8];
#pragma unroll
            for (int i = 0; i < 4; i++)
#pragma unroll
                for (int j = 0; j < 2; j++)
                    acc[i][j] = __builtin_amdgcn_mfma_f32_16x16x32_bf16(afr[i], bfr[j], acc[i][j], 0, 0, 0);
        }
    }

#pragma unroll
    for (int i = 0; i < 4; i++)
#pragma unroll
        for (int j = 0; j < 2; j++)
#pragma unroll
            for (int reg = 0; reg < 4; reg++) {
                int row = rowBase + wr * 64 + i * 16 + quad * 4 + reg;
                int col = colBase + wc * 32 + j * 16 + lo;
                size_t idx = (size_t)row * DD + col;
                if (fout) ((float*)Cout)[idx] = acc[i][j][reg];
                else      ((bf16_t*)Cout)[idx] = (bf16_t)acc[i][j][reg];
            }
}

// ---------------- OLD dtype-branching projection GEMMs (ws fallback) ----
#define BKF 32  // fallback k-step
#define KP 40   // LDS row stride in bf16 elems

__device__ __forceinline__ bf16x4 cvt4(float4 v) {
    bf16x4 o;
    o[0] = (bf16_t)v.x; o[1] = (bf16_t)v.y; o[2] = (bf16_t)v.z; o[3] = (bf16_t)v.w;
    return o;
}

__global__ __launch_bounds__(256) void proj_qkv(const void* __restrict__ X,
                                                const void* __restrict__ Wq,
                                                const void* __restrict__ Wk,
                                                const void* __restrict__ Wv,
                                                bf16_t* __restrict__ QA,
                                                bf16_t* __restrict__ Kp,
                                                bf16_t* __restrict__ VpT,
                                                const int* __restrict__ flag) {
    const int f = *flag;  // 1 => fp32 inputs

    __shared__ bf16_t As[128 * KP];
    __shared__ bf16_t Ws[64 * KP];

    const int tid = threadIdx.x;
    const int wave = tid >> 6, lane = tid & 63;
    const int lo = lane & 15, quad = lane >> 4;
    const int rb = wave * 32;
    const int cb = blockIdx.x;              // 0..17
    const int rowBase = blockIdx.y * 128;

    floatx4 acc[2][4];
#pragma unroll
    for (int i = 0; i < 2; i++)
#pragma unroll
        for (int j = 0; j < 4; j++) acc[i][j] = (floatx4){0.f, 0.f, 0.f, 0.f};

    if (f) {
        const int rA = tid >> 3, sg = tid & 7;
        const float* arow[4];
        const float* wrow[2];
#pragma unroll
        for (int p = 0; p < 4; p++)
            arow[p] = (const float*)X + (size_t)(rowBase + rA + 32 * p) * DD;
#pragma unroll
        for (int p = 0; p < 2; p++) {
            int row = rA + 32 * p;
            if (cb < 16)       wrow[p] = (const float*)Wq + (size_t)(cb * 64 + row) * DD;
            else if (cb == 16) wrow[p] = (const float*)Wk + (size_t)row * DD;
            else               wrow[p] = (const float*)Wv + (size_t)row * DD;
        }
        float4 aR[4], wR[2];
#pragma unroll
        for (int p = 0; p < 4; p++) aR[p] = *(const float4*)(arow[p] + sg * 4);
#pragma unroll
        for (int p = 0; p < 2; p++) wR[p] = *(const float4*)(wrow[p] + sg * 4);

        for (int k0 = 0; k0 < DD; k0 += BKF) {
            __syncthreads();
#pragma unroll
            for (int p = 0; p < 4; p++)
                *(bf16x4*)&As[(rA + 32 * p) * KP + sg * 4] = cvt4(aR[p]);
#pragma unroll
            for (int p = 0; p < 2; p++)
                *(bf16x4*)&Ws[(rA + 32 * p) * KP + sg * 4] = cvt4(wR[p]);
            __syncthreads();
            if (k0 + BKF < DD) {
#pragma unroll
                for (int p = 0; p < 4; p++) aR[p] = *(const float4*)(arow[p] + k0 + BKF + sg * 4);
#pragma unroll
                for (int p = 0; p < 2; p++) wR[p] = *(const float4*)(wrow[p] + k0 + BKF + sg * 4);
            }
            bf16x8 afr[2], bfr[4];
#pragma unroll
            for (int i = 0; i < 2; i++)
                afr[i] = *(const bf16x8*)&As[(rb + i * 16 + lo) * KP + quad * 8];
#pragma unroll
            for (int j = 0; j < 4; j++)
                bfr[j] = *(const bf16x8*)&Ws[(j * 16 + lo) * KP + quad * 8];
#pragma unroll
            for (int i = 0; i < 2; i++)
#pragma unroll
                for (int j = 0; j < 4; j++)
                    acc[i][j] = __builtin_amdgcn_mfma_f32_16x16x32_bf16(afr[i], bfr[j], acc[i][j], 0, 0, 0);
        }
    } else {
        const int rA = tid >> 2, sg = tid & 3;
        const bf16_t* arow[2];
        const bf16_t* wrow;
#pragma unroll
        for (int p = 0; p < 2; p++)
            arow[p] = (const bf16_t*)X + (size_t)(rowBase + rA + 64 * p) * DD;
        if (cb < 16)       wrow = (const bf16_t*)Wq + (size_t)(cb * 64 + rA) * DD;
        else if (cb == 16) wrow = (const bf16_t*)Wk + (size_t)rA * DD;
        else               wrow = (const bf16_t*)Wv + (size_t)rA * DD;
        bf16x8 aR[2], wR;
#pragma unroll
        for (int p = 0; p < 2; p++) aR[p] = *(const bf16x8*)(arow[p] + sg * 8);
        wR = *(const bf16x8*)(wrow + sg * 8);

        for (int k0 = 0; k0 < DD; k0 += BKF) {
            __syncthreads();
#pragma unroll
            for (int p = 0; p < 2; p++)
                *(bf16x8*)&As[(rA + 64 * p) * KP + sg * 8] = aR[p];
            *(bf16x8*)&Ws[rA * KP + sg * 8] = wR;
            __syncthreads();
            if (k0 + BKF < DD) {
#pragma unroll
                for (int p = 0; p < 2; p++) aR[p] = *(const bf16x8*)(arow[p] + k0 + BKF + sg * 8);
                wR = *(const bf16x8*)(wrow + k0 + BKF + sg * 8);
            }
            bf16x8 afr[2], bfr[4];
#pragma unroll
            for (int i = 0; i < 2; i++)
                afr[i] = *(const bf16x8*)&As[(rb + i * 16 + lo) * KP + quad * 8];
#pragma unroll
            for (int j = 0; j < 4; j++)
                bfr[j] = *(const bf16x8*)&Ws[(j * 16 + lo) * KP + quad * 8];
#pragma unroll
            for (int i = 0; i < 2; i++)
#pragma unroll
                for (int j = 0; j < 4; j++)
                    acc[i][j] = __builtin_amdgcn_mfma_f32_16x16x32_bf16(afr[i], bfr[j], acc[i][j], 0, 0, 0);
        }
    }

#pragma unroll
    for (int i = 0; i < 2; i++)
#pragma unroll
        for (int j = 0; j < 4; j++)
#pragma unroll
            for (int reg = 0; reg < 4; reg++) {
                int row = rowBase + rb + i * 16 + quad * 4 + reg;
                int col = j * 16 + lo;
                if (cb < 16) {
                    QA[(size_t)row * DD + cb * 64 + col] = (bf16_t)(acc[i][j][reg] * SCALEQ);
                } else if (cb == 16) {
                    Kp[(size_t)row * HD + col] = (bf16_t)acc[i][j][reg];
                } else {
                    VpT[((size_t)(row >> 11) * HD + col) * SS + (row & (SS - 1))] =
                        (bf16_t)acc[i][j][reg];
                }
            }
}

__global__ __launch_bounds__(256) void proj_o(const bf16_t* __restrict__ AO,
                                              const void* __restrict__ Wo,
                                              void* __restrict__ Cout,
                                              const int* __restrict__ flagW,
                                              const int* __restrict__ flagOut) {
    const int f = *flagW;
    const int fout = *flagOut;

    __shared__ bf16_t As[128 * KP];
    __shared__ bf16_t Ws[64 * KP];

    const int tid = threadIdx.x;
    const int wave = tid >> 6, lane = tid & 63;
    const int lo = lane & 15, quad = lane >> 4;
    const int rb = wave * 32;
    const int colBase = blockIdx.x * 64;
    const int rowBase = blockIdx.y * 128;

    floatx4 acc[2][4];
#pragma unroll
    for (int i = 0; i < 2; i++)
#pragma unroll
        for (int j = 0; j < 4; j++) acc[i][j] = (floatx4){0.f, 0.f, 0.f, 0.f};

    const int rA2 = tid >> 2, sgA = tid & 3;
    const bf16_t* arow[2] = {AO + (size_t)(rowBase + rA2) * DD,
                             AO + (size_t)(rowBase + rA2 + 64) * DD};
    bf16x8 aR[2];
#pragma unroll
    for (int p = 0; p < 2; p++) aR[p] = *(const bf16x8*)(arow[p] + sgA * 8);

    if (f) {
        const int rW = tid >> 3, sgW = tid & 7;
        const float* wrow[2];
#pragma unroll
        for (int p = 0; p < 2; p++)
            wrow[p] = (const float*)Wo + (size_t)(colBase + rW + 32 * p) * DD;
        float4 wR[2];
#pragma unroll
        for (int p = 0; p < 2; p++) wR[p] = *(const float4*)(wrow[p] + sgW * 4);

        for (int k0 = 0; k0 < DD; k0 += BKF) {
            __syncthreads();
#pragma unroll
            for (int p = 0; p < 2; p++)
                *(bf16x8*)&As[(rA2 + 64 * p) * KP + sgA * 8] = aR[p];
#pragma unroll
            for (int p = 0; p < 2; p++)
                *(bf16x4*)&Ws[(rW + 32 * p) * KP + sgW * 4] = cvt4(wR[p]);
            __syncthreads();
            if (k0 + BKF < DD) {
#pragma unroll
                for (int p = 0; p < 2; p++) aR[p] = *(const bf16x8*)(arow[p] + k0 + BKF + sgA * 8);
#pragma unroll
                for (int p = 0; p < 2; p++) wR[p] = *(const float4*)(wrow[p] + k0 + BKF + sgW * 4);
            }
            bf16x8 afr[2], bfr[4];
#pragma unroll
            for (int i = 0; i < 2; i++)
                afr[i] = *(const bf16x8*)&As[(rb + i * 16 + lo) * KP + quad * 8];
#pragma unroll
            for (int j = 0; j < 4; j++)
                bfr[j] = *(const bf16x8*)&Ws[(j * 16 + lo) * KP + quad * 8];
#pragma unroll
            for (int i = 0; i < 2; i++)
#pragma unroll
                for (int j = 0; j < 4; j++)
                    acc[i][j] = __builtin_amdgcn_mfma_f32_16x16x32_bf16(afr[i], bfr[j], acc[i][j], 0, 0, 0);
        }
    } else {
        const bf16_t* wrow = (const bf16_t*)Wo + (size_t)(colBase + rA2) * DD;
        bf16x8 wR = *(const bf16x8*)(wrow + sgA * 8);

        for (int k0 = 0; k0 < DD; k0 += BKF) {
            __syncthreads();
#pragma unroll
            for (int p = 0; p < 2; p++)
                *(bf16x8*)&As[(rA2 + 64 * p) * KP + sgA * 8] = aR[p];
            *(bf16x8*)&Ws[rA2 * KP + sgA * 8] = wR;
            __syncthreads();
            if (k0 + BKF < DD) {
#pragma unroll
                for (int p = 0; p < 2; p++) aR[p] = *(const bf16x8*)(arow[p] + k0 + BKF + sgA * 8);
                wR = *(const bf16x8*)(wrow + k0 + BKF + sgA * 8);
            }
            bf16x8 afr[2], bfr[4];
#pragma unroll
            for (int i = 0; i < 2; i++)
                afr[i] = *(const bf16x8*)&As[(rb + i * 16 + lo) * KP + quad * 8];
#pragma unroll
            for (int j = 0; j < 4; j++)
                bfr[j] = *(const bf16x8*)&Ws[(j * 16 + lo) * KP + quad * 8];
#pragma unroll
            for (int i = 0; i < 2; i++)
#pragma unroll
                for (int j = 0; j < 4; j++)
                    acc[i][j] = __builtin_amdgcn_mfma_f32_16x16x32_bf16(afr[i], bfr[j], acc[i][j], 0, 0, 0);
        }
    }

#pragma unroll
    for (int i = 0; i < 2; i++)
#pragma unroll
        for (int j = 0; j < 4; j++)
#pragma unroll
            for (int reg = 0; reg < 4; reg++) {
                int row = rowBase + rb + i * 16 + quad * 4 + reg;
                int col = colBase + j * 16 + lo;
                size_t idx = (size_t)row * DD + col;
                if (fout) ((float*)Cout)[idx] = acc[i][j][reg];
                else      ((bf16_t*)Cout)[idx] = (bf16_t)acc[i][j][reg];
            }
}

// ---------------- barrier-free MFMA flash attention, balanced key-split ----
// 512-thread blocks (8 waves), pair (x, 63-x): 65 key-tiles per block by
// construction; waves assigned proportionally (worst ~10 tiles). Defer-max
// softmax (shuffle-free common case). __launch_bounds__(512, 4): 128-VGPR
// budget. PROVEN: (512,8)->64-reg and (512,6)->85-reg caps BOTH spill
// catastrophically (0.6-1.5 GB scratch traffic); the wave's live set needs
// the full 128-reg bin. Do not lower this cap again.
#define PSTR 40
#define DMTHR 8.0f    // defer-max threshold (exp2 domain)

__global__ __launch_bounds__(512, 4) void attn_mfma(const bf16_t* Q,
                                                    const bf16_t* __restrict__ K,
                                                    const bf16_t* __restrict__ Vt,
                                                    bf16_t* O) {
    const int h = blockIdx.y, b = blockIdx.z;
    const int tid = threadIdx.x;
    const int wq = tid >> 6, lane = tid & 63;
    const int lo = lane & 15, quad = lane >> 4;
    const int x = blockIdx.x;           // 0..31 -> pair (x, 63-x)

    // --- proportional wave->q-tile assignment (minimize max wave tiles) ---
    const int nA = x + 1;               // key-tiles for qt = x (pair total 65)
    int na = 1, bestc = 0x7fffffff;
#pragma unroll
    for (int a = 1; a <= 7; ++a) {
        int cA = (nA + a - 1) / a;
        int cB = (65 - nA + (7 - a)) / (8 - a);
        int c = cA > cB ? cA : cB;
        if (c < bestc) { bestc = c; na = a; }
    }
    int qt, pos, gs;
    if (wq < na) { qt = x;      pos = wq;      gs = na; }
    else         { qt = 63 - x; pos = wq - na; gs = 8 - na; }
    const int q0 = qt * 32;
    const int n = qt + 1;               // total key-tiles for this q-tile
    const int itS = (n * pos) / gs;
    const int itE = (n * (pos + 1)) / gs;

    // --- LDS: P staging (per-wave, loop phase) unions merge buffers ---
    __shared__ __align__(16) char smem[4 * 32 * 64 * 4];  // 32768 B
    __shared__ float MrgML[4][2][2][16];                  // [buf][s][m/l][lo]
    bf16_t* Pw = (bf16_t*)smem + wq * (32 * PSTR);        // 8 x 2560 B = 20480 B
    float (*MrgO)[32 * 64] = (float (*)[32 * 64])smem;    // 4 bufs x 8 KB

    // Q frags (B operand: n=q, k=dim); Q already scaled by (1/8)*log2(e)
    bf16x8 qf[2][2];
#pragma unroll
    for (int s = 0; s < 2; s++)
#pragma unroll
        for (int hf = 0; hf < 2; hf++)
            qf[s][hf] = *(const bf16x8*)(Q + ((size_t)(b * SS + q0 + s * 16 + lo)) * DD +
                                         h * HD + hf * 32 + quad * 8);

    floatx4 Oacc[2][4];
    float m_i[2], l_ln[2];   // m: column-consistent running max; l: LANE-partial
#pragma unroll
    for (int s = 0; s < 2; s++) {
#pragma unroll
        for (int dt = 0; dt < 4; dt++) Oacc[s][dt] = (floatx4){0.f, 0.f, 0.f, 0.f};
        m_i[s] = -1e30f; l_ln[s] = 0.f;
    }

    const bf16_t* Kb = K + (size_t)b * SS * HD;
    const bf16_t* Vb = Vt + (size_t)b * HD * SS;

    if (itS < itE) {
        // preload K tile itS
        bf16x8 kf[2][2];
#pragma unroll
        for (int kt = 0; kt < 2; kt++)
#pragma unroll
            for (int hf = 0; hf < 2; hf++)
                kf[kt][hf] = *(const bf16x8*)(Kb + (size_t)(itS * 32 + kt * 16 + lo) * HD +
                                              hf * 32 + quad * 8);

        for (int it = itS; it < itE; it++) {
            const int t0 = it * 32;

            bf16x8 vf[4];
#pragma unroll
            for (int dt = 0; dt < 4; dt++)
                vf[dt] = *(const bf16x8*)(Vb + (size_t)(dt * 16 + lo) * SS + t0 + quad * 8);

            bf16x8 kn[2][2];
            if (it + 1 < itE) {
#pragma unroll
                for (int kt = 0; kt < 2; kt++)
#pragma unroll
                    for (int hf = 0; hf < 2; hf++)
                        kn[kt][hf] = *(const bf16x8*)(Kb + (size_t)(t0 + 32 + kt * 16 + lo) * HD +
                                                      hf * 32 + quad * 8);
            }

            // S^T = K.Q^T  (already in exp2 domain via pre-scaled Q)
            floatx4 st[2][2];
#pragma unroll
            for (int s = 0; s < 2; s++)
#pragma unroll
                for (int kt = 0; kt < 2; kt++) {
                    floatx4 z = (floatx4){0.f, 0.f, 0.f, 0.f};
                    z = __builtin_amdgcn_mfma_f32_16x16x32_bf16(kf[kt][0], qf[s][0], z, 0, 0, 0);
                    z = __builtin_amdgcn_mfma_f32_16x16x32_bf16(kf[kt][1], qf[s][1], z, 0, 0, 0);
                    st[s][kt] = z;
                }

            if (it == qt) {  // diagonal tile (always last pos of the group)
#pragma unroll
                for (int s = 0; s < 2; s++) {
                    int q = q0 + s * 16 + lo;
#pragma unroll
                    for (int kt = 0; kt < 2; kt++)
#pragma unroll
                        for (int reg = 0; reg < 4; reg++)
                            if (t0 + kt * 16 + quad * 4 + reg > q) st[s][kt][reg] = -1e30f;
                }
            }

            // defer-max online softmax: shuffle-free in the common case
#pragma unroll
            for (int s = 0; s < 2; s++) {
                float lm = fmaxf(fmaxf(fmaxf(st[s][0][0], st[s][0][1]), fmaxf(st[s][0][2], st[s][0][3])),
                                 fmaxf(fmaxf(st[s][1][0], st[s][1][1]), fmaxf(st[s][1][2], st[s][1][3])));
                if (__any(lm > m_i[s] + DMTHR)) {
                    float mx = fmaxf(lm, __shfl_xor(lm, 16));
                    mx = fmaxf(mx, __shfl_xor(mx, 32));
                    float mn = fmaxf(m_i[s], mx);
                    float al = exp2f(m_i[s] - mn);
                    m_i[s] = mn;
                    l_ln[s] *= al;
#pragma unroll
                    for (int dt = 0; dt < 4; dt++) Oacc[s][dt] *= al;
                }
                float p[2][4];
#pragma unroll
                for (int kt = 0; kt < 2; kt++)
#pragma unroll
                    for (int reg = 0; reg < 4; reg++)
                        p[kt][reg] = exp2f(st[s][kt][reg] - m_i[s]);
                l_ln[s] += ((p[0][0] + p[0][1]) + (p[0][2] + p[0][3])) +
                           ((p[1][0] + p[1][1]) + (p[1][2] + p[1][3]));
#pragma unroll
                for (int kt = 0; kt < 2; kt++) {
                    bf16x4 pk;
#pragma unroll
                    for (int reg = 0; reg < 4; reg++) pk[reg] = (bf16_t)p[kt][reg];
                    *(bf16x4*)&Pw[(s * 16 + lo) * PSTR + kt * 16 + quad * 4] = pk;
                }
            }

            asm volatile("s_waitcnt lgkmcnt(0)" ::: "memory");

            // O^T += V^T . P^T
            bf16x8 pb[2];
#pragma unroll
            for (int s = 0; s < 2; s++)
                pb[s] = *(const bf16x8*)&Pw[(s * 16 + lo) * PSTR + quad * 8];
#pragma unroll
            for (int s = 0; s < 2; s++)
#pragma unroll
                for (int dt = 0; dt < 4; dt++)
                    Oacc[s][dt] = __builtin_amdgcn_mfma_f32_16x16x32_bf16(vf[dt], pb[s], Oacc[s][dt], 0, 0, 0);

#pragma unroll
            for (int kt = 0; kt < 2; kt++)
#pragma unroll
                for (int hf = 0; hf < 2; hf++) kf[kt][hf] = kn[kt][hf];
        }
    }

    // ---- finalize lane-partial l into column-consistent l_i ----
    float l_i[2];
#pragma unroll
    for (int s = 0; s < 2; s++) {
        float l = l_ln[s];
        l += __shfl_xor(l, 16);
        l += __shfl_xor(l, 32);
        l_i[s] = l;
    }

    // ---- binary-tree merge within each wave group (flash merge algebra) ----
    for (int step = 1; step < 8; step <<= 1) {
        const bool pub = (pos & (2 * step - 1)) == step;
        const bool cmb = ((pos & (2 * step - 1)) == 0) && (pos + step < gs);
        __syncthreads();   // previous round's reads (and P-staging use) done
        if (pub) {
            float* Ob = MrgO[wq >> 1];
#pragma unroll
            for (int s = 0; s < 2; s++) {
#pragma unroll
                for (int dt = 0; dt < 4; dt++)
#pragma unroll
                    for (int reg = 0; reg < 4; reg++)
                        Ob[(s * 16 + dt * 4 + reg) * 64 + lane] = Oacc[s][dt][reg];
                if (quad == 0) {
                    MrgML[wq >> 1][s][0][lo] = m_i[s];
                    MrgML[wq >> 1][s][1][lo] = l_i[s];
                }
            }
        }
        __syncthreads();
        if (cmb) {
            const int bu = (wq + step) >> 1;
            const float* Ob = MrgO[bu];
#pragma unroll
            for (int s = 0; s < 2; s++) {
                float m1 = MrgML[bu][s][0][lo];
                float l1 = MrgML[bu][s][1][lo];
                float mm = fmaxf(m_i[s], m1);
                float a0 = exp2f(m_i[s] - mm);
                float a1 = exp2f(m1 - mm);
                m_i[s] = mm;
                l_i[s] = l_i[s] * a0 + l1 * a1;
#pragma unroll
                for (int dt = 0; dt < 4; dt++)
#pragma unroll
                    for (int reg = 0; reg < 4; reg++)
                        Oacc[s][dt][reg] = Oacc[s][dt][reg] * a0 +
                                           Ob[(s * 16 + dt * 4 + reg) * 64 + lane] * a1;
            }
        }
    }

    // ---- group leaders (pos==0: waves 0 and na) finalize + store ----
    if (pos == 0) {
#pragma unroll
        for (int s = 0; s < 2; s++) {
            float linv = 1.f / l_i[s];
            bf16_t* Orow = O + ((size_t)(b * SS + q0 + s * 16 + lo)) * DD + h * HD;
#pragma unroll
            for (int dt = 0; dt < 4; dt++) {
                bf16x4 ov;
#pragma unroll
                for (int reg = 0; reg < 4; reg++)
                    ov[reg] = (bf16_t)(Oacc[s][dt][reg] * linv);
                *(bf16x4*)&Orow[dt * 16 + quad * 4] = ov;
            }
        }
    }
}

// ---------------- launch ----------------
extern "C" void kernel_launch(void* const* d_in, const int* in_sizes, int n_in,
                              void* d_out, int out_size, void* d_ws, size_t ws_size,
                              hipStream_t stream) {
    const void* x  = d_in[0];
    const void* Wq = d_in[1];
    const void* Wk = d_in[2];
    const void* Wv = d_in[3];
    const void* Wo = d_in[4];
    // d_in[5] = causal mask — known tril, handled analytically in attn_mfma.

    // Workspace layout:
    // [flag 2xint, 256B] | QA bf16[4096,1024] | Kp bf16[4096,64] |
    // VpT bf16[2][64][2048] | Xb bf16[4096,1024] | Wqb bf16[1024,1024] |
    // Wkb bf16[64,1024] | Wvb bf16[64,1024] | Wob bf16[1024,1024]
    char* ws = (char*)d_ws;
    int* flag = (int*)ws;
    bf16_t* QA  = (bf16_t*)(ws + 256);
    bf16_t* Kp  = QA + (size_t)MM * DD;
    bf16_t* VpT = Kp + (size_t)MM * HD;
    bf16_t* Xb  = VpT + (size_t)BB * HD * SS;
    bf16_t* Wqb = Xb + (size_t)MM * DD;
    bf16_t* Wkb = Wqb + (size_t)DD * DD;
    bf16_t* Wvb = Wkb + (size_t)HD * DD;
    bf16_t* Wob = Wvb + (size_t)HD * DD;
    size_t need = (size_t)((char*)(Wob + (size_t)DD * DD) - ws);

    detect_dtype<<<1, 64, 0, stream>>>((const unsigned int*)x, flag);

    if (ws_size >= need) {
        // Convert all operands to bf16 once; projections run the fat-tile
        // bf16-only path (128x128, 512 thr, BK=64, depth-2 reg prefetch,
        // transposed grid for XCD L2 locality).
        conv_all<<<dim3(1024), dim3(256), 0, stream>>>(x, Wq, Wk, Wv, Wo,
                                                       Xb, Wqb, Wkb, Wvb, Wob, flag);
        proj_qkv_b<<<dim3(MM / 128, 9), dim3(512), 0, stream>>>(Xb, Wqb, Wkb, Wvb,
                                                                QA, Kp, VpT);
        attn_mfma<<<dim3(32, NH, BB), dim3(512), 0, stream>>>(QA, Kp, VpT, QA);
        proj_o_b<<<dim3(MM / 128, 8), dim3(512), 0, stream>>>(QA, Wob, d_out, flag);
    } else {
        // Fallback: original direct-from-input path.
        proj_qkv<<<dim3(18, MM / 128), dim3(256), 0, stream>>>(x, Wq, Wk, Wv,
                                                               QA, Kp, VpT, flag);
        attn_mfma<<<dim3(32, NH, BB), dim3(512), 0, stream>>>(QA, Kp, VpT, QA);
        proj_o<<<dim3(16, MM / 128), dim3(256), 0, stream>>>(QA, Wo, d_out,
                                                             flag, flag);
    }
}